// Round 12
// baseline (171.251 us; speedup 1.0000x reference)
//
#include <hip/hip_runtime.h>

typedef float f32x4 __attribute__((ext_vector_type(4)));
typedef __bf16 bf16x8 __attribute__((ext_vector_type(8)));
typedef __bf16 bf16x4 __attribute__((ext_vector_type(4)));

constexpr float INV_SQRT_F = 0.17677669529663687f;  // 32^-0.5

__device__ __forceinline__ f32x4 mfma16(bf16x8 a, bf16x8 b) {
  const f32x4 z = {0.f, 0.f, 0.f, 0.f};
  return __builtin_amdgcn_mfma_f32_16x16x32_bf16(a, b, z, 0, 0, 0);
}
__device__ __forceinline__ f32x4 ld4(const float* p) {
  return *reinterpret_cast<const f32x4*>(p);
}
__device__ __forceinline__ bf16x8 ldb8(const __bf16* __restrict__ p) {
  return *reinterpret_cast<const bf16x8*>(p);
}
__device__ __forceinline__ bf16x8 cvt_frag(f32x4 u, f32x4 v) {
  bf16x8 r;
  r[0] = (__bf16)u[0]; r[1] = (__bf16)u[1]; r[2] = (__bf16)u[2]; r[3] = (__bf16)u[3];
  r[4] = (__bf16)v[0]; r[5] = (__bf16)v[1]; r[6] = (__bf16)v[2]; r[7] = (__bf16)v[3];
  return r;
}
// async global->LDS DMA, 16B/lane: gp per-lane source, lp wave-uniform dest.
__device__ __forceinline__ void stage16(const float* gp, float* lp) {
  __builtin_amdgcn_global_load_lds(
      (const __attribute__((address_space(1))) void*)gp,
      (__attribute__((address_space(3))) void*)lp, 16, 0, 0);
}

// ---------------- pre-pass: h -> bf16, W -> scaled frag-layout bf16 --------
__global__ __launch_bounds__(256)
void leibniz_prepass(const float* __restrict__ h0, const float* __restrict__ h1,
                     const float* __restrict__ h2, const float* __restrict__ Wg,
                     __bf16* __restrict__ ws, int n0, int n1, int n2)
{
  if (blockIdx.x == 0) {
    bf16x8* wsW = reinterpret_cast<bf16x8*>(ws);
    for (int c = threadIdx.x; c < 12 * 2 * 4 * 16; c += 256) {
      const int gl = c & 15;
      const int qq = (c >> 4) & 3;
      const int hf = (c >> 6) & 1;
      const int p  = c >> 7;
      const float* wp = Wg + (p * 32 + hf * 16 + gl) * 32 + qq * 8;
      bf16x8 f;
#pragma unroll
      for (int j = 0; j < 8; ++j) f[j] = (__bf16)(wp[j] * INV_SQRT_F);
      wsW[c] = f;
    }
  }
  __bf16* hb0 = ws + 12288;
  __bf16* hb1 = hb0 + n0;
  __bf16* hb2 = hb1 + n1;
  const int q0 = n0 >> 2, q1 = n1 >> 2, q2 = n2 >> 2;
  const int total = q0 + q1 + q2;
  for (int i = blockIdx.x * 256 + threadIdx.x; i < total; i += gridDim.x * 256) {
    const float* sp;
    __bf16* dp;
    if (i < q0)           { sp = h0 + 4 * i;              dp = hb0 + 4 * i; }
    else if (i < q0 + q1) { int j = i - q0;      sp = h1 + 4 * j; dp = hb1 + 4 * j; }
    else                  { int j = i - q0 - q1; sp = h2 + 4 * j; dp = hb2 + 4 * j; }
    const f32x4 v = *reinterpret_cast<const f32x4*>(sp);
    bf16x4 o;
    o[0] = (__bf16)v[0]; o[1] = (__bf16)v[1]; o[2] = (__bf16)v[2]; o[3] = (__bf16)v[3];
    *reinterpret_cast<bf16x4*>(dp) = o;
  }
}

// ---------------- main: half-split DMA double-buffered pipeline ------------
// Block = 2 waves = one 16-edge tile sequence; wave parity = feature half.
// Per iteration: vmcnt(0) drain -> DMA-stage tile t+1's g-half into buf^1 +
// batch h(t+1) gather + src(t+2) prefetch -> compute+store tile t from
// buf[cur]. Stage of t+1 is in flight during the ENTIRE compute of t (duty
// ~1.0 — fixes R11's 0.1 duty; R9 proved the skeleton at 3 waves/CU, this
// runs 6 via 53KB static LDS + W in 12 regs/wave instead of LDS).
// LDS region (per wave, per buf): 13 rows x 1KB; lane L holds its own 16B
// at L*16 (DMA dest linear, source per-lane pre-permuted) -> ds_read_b128
// at lane*16, conflict-free. Pair covers the two 64B sectors of every
// g/out line (s_barrier-aligned).
__global__ __launch_bounds__(128, 2)
void leibniz_dma(const __bf16* __restrict__ wsAll,
                 const float* __restrict__ g0, const float* __restrict__ g1,
                 const float* __restrict__ g2, const int* __restrict__ src,
                 float* __restrict__ out, int E, int n0, int n1)
{
  __shared__ __align__(16) float smem[4 * 3328];  // 53,248 B: [half][buf] regions

  const int lane = threadIdx.x & 63;
  const int half = threadIdx.x >> 6;   // wave id within block
  const int eidx = lane & 15;          // edge within tile
  const int q    = lane >> 4;          // feature quad (within half)

  // W fragments for MY half -> 12 x bf16x8 (48 VGPRs)
  bf16x8 w[12];
  {
    const bf16x8* wsW = reinterpret_cast<const bf16x8*>(wsAll);
#pragma unroll
    for (int p = 0; p < 12; ++p) w[p] = wsW[(p * 2 + half) * 64 + q * 16 + eidx];
  }
  const __bf16* hb0 = wsAll + 12288;
  const __bf16* hb1 = hb0 + n0;
  const __bf16* hb2 = hb1 + n1;

  const int NT  = (E + 15) >> 4;
  const int NBg = gridDim.x;
  const long long o1base = (long long)E * 32;
  const long long o2base = (long long)E * 128;
  const int col = q * 4 + 16 * half;

#define EBASE(T) ((long long)(T) * 16 > (long long)E - 16 ? (long long)E - 16 \
                                                          : (long long)(T) * 16)

#define STAGE(TILE, BUF) do {                                                  \
  const long long eb_ = EBASE(TILE);                                           \
  float* lb_ = smem + (half * 2 + (BUF)) * 3328;                               \
  const float* s0_ = g0 + (eb_ + eidx) * 32 + col;                             \
  stage16(s0_, lb_);                                                           \
  const float* s1_ = g1 + (eb_ + eidx) * 96 + col;                             \
  _Pragma("unroll")                                                            \
  for (int s = 0; s < 3; ++s) stage16(s1_ + s * 32, lb_ + (1 + s) * 256);      \
  const float* s2_ = g2 + (eb_ + eidx) * 288 + col;                            \
  _Pragma("unroll")                                                            \
  for (int ss = 0; ss < 9; ++ss) stage16(s2_ + ss * 32, lb_ + (4 + ss) * 256); \
} while (0)

#define LOAD_H(NODE, B0, B1, B2) do {                                          \
  const __bf16* p0_ = hb0 + (long long)(NODE) * 32 + q * 8;                    \
  B0 = ldb8(p0_);                                                              \
  const __bf16* p1_ = hb1 + (long long)(NODE) * 96 + q * 8;                    \
  _Pragma("unroll") for (int s = 0; s < 3; ++s) B1[s] = ldb8(p1_ + s * 32);    \
  const __bf16* p2_ = hb2 + (long long)(NODE) * 288 + q * 8;                   \
  _Pragma("unroll") for (int s = 0; s < 9; ++s) B2[s] = ldb8(p2_ + s * 32);    \
} while (0)

#define COMPUTE_STORE(TILE, CUR, B0, B1, B2) do {                              \
  const long long e_ = EBASE(TILE) + eidx;                                     \
  const float* lb = smem + (half * 2 + (CUR)) * 3328 + lane * 4;               \
  /* g0 phase: paths 0,3,4 (prod); accs initialized here */                    \
  const f32x4 gv0 = ld4(lb);                                                   \
  f32x4 acc0 = mfma16(w[0], B0) * gv0;                                         \
  f32x4 acc1[3];                                                               \
  f32x4 acc2[9];                                                               \
  {                                                                            \
    _Pragma("unroll")                                                          \
    for (int s = 0; s < 3; ++s) acc1[s] = mfma16(w[3], B1[s]) * gv0;           \
    _Pragma("unroll")                                                          \
    for (int s = 0; s < 9; ++s) acc2[s] = mfma16(w[4], B2[s]) * gv0;           \
  }                                                                            \
  /* g1 phase: paths 1,5,6,7,8 */                                              \
  {                                                                            \
    f32x4 gv1[3];                                                              \
    _Pragma("unroll")                                                          \
    for (int s = 0; s < 3; ++s) gv1[s] = ld4(lb + (1 + s) * 256);              \
    {                                                                          \
      const f32x4 t = mfma16(w[1], B0);                                        \
      _Pragma("unroll")                                                        \
      for (int s = 0; s < 3; ++s) acc1[s] += t * gv1[s];                       \
    }                                                                          \
    _Pragma("unroll")                                                          \
    for (int s = 0; s < 3; ++s) acc0 += mfma16(w[5], B1[s]) * gv1[s];          \
    {                                                                          \
      const f32x4 c0 = mfma16(w[6], B1[0]);                                    \
      const f32x4 c1 = mfma16(w[6], B1[1]);                                    \
      const f32x4 c2 = mfma16(w[6], B1[2]);                                    \
      acc1[0] += c1 * gv1[2] - c2 * gv1[1];                                    \
      acc1[1] += c2 * gv1[0] - c0 * gv1[2];                                    \
      acc1[2] += c0 * gv1[1] - c1 * gv1[0];                                    \
    }                                                                          \
    {                                                                          \
      const f32x4 o0 = mfma16(w[7], B1[0]);                                    \
      const f32x4 o1 = mfma16(w[7], B1[1]);                                    \
      const f32x4 o2 = mfma16(w[7], B1[2]);                                    \
      const f32x4 tr3 =                                                        \
          (o0 * gv1[0] + o1 * gv1[1] + o2 * gv1[2]) * (1.f / 3.f);             \
      acc2[0] += o0 * gv1[0] - tr3;                                            \
      acc2[1] += o0 * gv1[1];                                                  \
      acc2[2] += o0 * gv1[2];                                                  \
      acc2[3] += o1 * gv1[0];                                                  \
      acc2[4] += o1 * gv1[1] - tr3;                                            \
      acc2[5] += o1 * gv1[2];                                                  \
      acc2[6] += o2 * gv1[0];                                                  \
      acc2[7] += o2 * gv1[1];                                                  \
      acc2[8] += o2 * gv1[2] - tr3;                                            \
    }                                                                          \
    _Pragma("unroll")                                                          \
    for (int a = 0; a < 3; ++a)                                                \
      _Pragma("unroll")                                                        \
      for (int b = 0; b < 3; ++b)                                              \
        acc1[a] += mfma16(w[8], B2[a * 3 + b]) * gv1[b];                       \
  }                                                                            \
  /* g2 phase: paths 2,9,10,11; per-k LDS row reads (3 f32x4 live) */          \
  {                                                                            \
    const f32x4 t2 = mfma16(w[2], B0);                                         \
    _Pragma("unroll")                                                          \
    for (int k = 0; k < 3; ++k) {                                              \
      f32x4 gk[3];                                                             \
      _Pragma("unroll")                                                        \
      for (int j = 0; j < 3; ++j) gk[j] = ld4(lb + (4 + k * 3 + j) * 256);     \
      _Pragma("unroll")                                                        \
      for (int j = 0; j < 3; ++j) acc2[k * 3 + j] += t2 * gk[j];               \
      {                                                                        \
        const f32x4 vk = mfma16(w[9], B1[k]);                                  \
        _Pragma("unroll")                                                      \
        for (int j = 0; j < 3; ++j) acc1[j] += vk * gk[j];                     \
      }                                                                        \
      _Pragma("unroll")                                                        \
      for (int j = 0; j < 3; ++j)                                              \
        acc0 += mfma16(w[10], B2[k * 3 + j]) * gk[j];                          \
      {                                                                        \
        const f32x4 m0 = mfma16(w[11], B2[0 * 3 + k]);                         \
        const f32x4 m1 = mfma16(w[11], B2[1 * 3 + k]);                         \
        const f32x4 m2 = mfma16(w[11], B2[2 * 3 + k]);                         \
        const f32x4 tk3 = (m0 * gk[0] + m1 * gk[1] + m2 * gk[2]) * (1.f/3.f);  \
        acc2[0] += m0 * gk[0] - tk3;                                           \
        acc2[4] += m1 * gk[1] - tk3;                                           \
        acc2[8] += m2 * gk[2] - tk3;                                           \
        const f32x4 s01 = (m0 * gk[1] + m1 * gk[0]) * 0.5f;                    \
        acc2[1] += s01; acc2[3] += s01;                                        \
        const f32x4 s02 = (m0 * gk[2] + m2 * gk[0]) * 0.5f;                    \
        acc2[2] += s02; acc2[6] += s02;                                        \
        const f32x4 s12 = (m1 * gk[2] + m2 * gk[1]) * 0.5f;                    \
        acc2[5] += s12; acc2[7] += s12;                                        \
      }                                                                        \
    }                                                                          \
  }                                                                            \
  /* stores: 16B/row; pair covers both 64B sectors of each 128B line */       \
  {                                                                            \
    float* o0p = out + e_ * 32 + col;                                          \
    float* o1p = out + o1base + e_ * 96 + col;                                 \
    float* o2p = out + o2base + e_ * 288 + col;                                \
    *reinterpret_cast<f32x4*>(o0p) = acc0;                                     \
    _Pragma("unroll")                                                          \
    for (int s = 0; s < 3; ++s)                                                \
      *reinterpret_cast<f32x4*>(o1p + s * 32) = acc1[s];                       \
    _Pragma("unroll")                                                          \
    for (int s = 0; s < 9; ++s)                                                \
      *reinterpret_cast<f32x4*>(o2p + s * 32) = acc2[s];                       \
  }                                                                            \
} while (0)

  // ---- prologue
  int tile = blockIdx.x;
  if (tile >= NT) return;

  const int nodeA0 = src[EBASE(tile) + eidx];
  STAGE(tile, 0);
  bf16x8 bA0, bA1[3], bA2[9];
  bf16x8 bB0, bB1[3], bB2[9];
  LOAD_H(nodeA0, bA0, bA1, bA2);
  int nnext = 0;
  if (tile + NBg < NT) nnext = src[EBASE(tile + NBg) + eidx];
  int cur = 0;

#define ITER(BC0, BC1, BC2, BN0, BN1, BN2)                                     \
  {                                                                            \
    asm volatile("s_waitcnt vmcnt(0)" ::: "memory");                           \
    __builtin_amdgcn_sched_barrier(0);                                         \
    __builtin_amdgcn_s_barrier(); /* pair align; no drain */                   \
    const int tn_ = tile + NBg;                                                \
    const bool hn_ = tn_ < NT;                                                 \
    if (hn_) {                                                                 \
      STAGE(tn_, cur ^ 1);                                                     \
      LOAD_H(nnext, BN0, BN1, BN2);                                            \
      const int t2_ = tile + 2 * NBg;                                          \
      if (t2_ < NT) nnext = src[EBASE(t2_) + eidx];                            \
    }                                                                          \
    COMPUTE_STORE(tile, cur, BC0, BC1, BC2);                                   \
    if (!hn_) break;                                                           \
    tile = tn_;                                                                \
    cur ^= 1;                                                                  \
  }

  for (;;) {
    ITER(bA0, bA1, bA2, bB0, bB1, bB2)
    ITER(bB0, bB1, bB2, bA0, bA1, bA2)
  }

#undef ITER
#undef COMPUTE_STORE
#undef LOAD_H
#undef STAGE
#undef EBASE
}

// ---------------- fallback: R5 fused kernel (127 us, no ws needed) ---------
__device__ __forceinline__ bf16x8 load_frag8(const float* __restrict__ p) {
  return cvt_frag(ld4(p), ld4(p + 4));
}
__device__ __forceinline__ f32x4 ntload4(const float* __restrict__ p) {
  return __builtin_nontemporal_load(reinterpret_cast<const f32x4*>(p));
}
__device__ __forceinline__ void ntstore4(float* __restrict__ p, f32x4 v) {
  __builtin_nontemporal_store(v, reinterpret_cast<f32x4*>(p));
}

__global__ __launch_bounds__(256, 2)
void leibniz_fused(const float* __restrict__ h0, const float* __restrict__ h1,
                   const float* __restrict__ h2, const float* __restrict__ g0,
                   const float* __restrict__ g1, const float* __restrict__ g2,
                   const float* __restrict__ Wg, const int* __restrict__ src,
                   float* __restrict__ out, int E)
{
  __shared__ bf16x8 wlds[12 * 2 * 4 * 16];
  for (int c = threadIdx.x; c < 12 * 2 * 4 * 16; c += 256) {
    const int gl = c & 15;
    const int qq = (c >> 4) & 3;
    const int hf = (c >> 6) & 1;
    const int p  = c >> 7;
    const float* wp = Wg + (p * 32 + hf * 16 + gl) * 32 + qq * 8;
    bf16x8 f;
#pragma unroll
    for (int j = 0; j < 8; ++j) f[j] = (__bf16)(wp[j] * INV_SQRT_F);
    wlds[c] = f;
  }
  __syncthreads();

  const int lane = threadIdx.x & 63;
  const int wid  = threadIdx.x >> 6;
  const int eidx = lane & 15;
  const int q    = lane >> 4;
  int e0 = (blockIdx.x * 4 + wid) * 16;
  if (e0 > E - 16) e0 = E - 16;

  const int node = src[e0 + eidx];
  const int e   = e0 + eidx;
  const int col = q * 4;
  const float* g0p = g0 + e * 32 + col;
  const float* g1p = g1 + (long long)e * 96 + col;
  const float* g2p = g2 + (long long)e * 288 + col;

  f32x4 gv0[2];
  gv0[0] = ntload4(g0p); gv0[1] = ntload4(g0p + 16);
  f32x4 gv1[3][2];
#pragma unroll
  for (int s = 0; s < 3; ++s) {
    gv1[s][0] = ntload4(g1p + s * 32);
    gv1[s][1] = ntload4(g1p + s * 32 + 16);
  }

  const int k0 = q * 8;
  const bf16x8 b0 = load_frag8(h0 + node * 32 + k0);
  bf16x8 b1[3];
#pragma unroll
  for (int s = 0; s < 3; ++s) b1[s] = load_frag8(h1 + node * 96 + s * 32 + k0);
  bf16x8 b2[9];
#pragma unroll
  for (int s = 0; s < 9; ++s) b2[s] = load_frag8(h2 + node * 288 + s * 32 + k0);

  const f32x4 z4 = {0.f, 0.f, 0.f, 0.f};
  f32x4 acc0[2] = {z4, z4};
  f32x4 acc1[3][2];
  f32x4 acc2[9][2];
#pragma unroll
  for (int s = 0; s < 3; ++s) { acc1[s][0] = z4; acc1[s][1] = z4; }
#pragma unroll
  for (int s = 0; s < 9; ++s) { acc2[s][0] = z4; acc2[s][1] = z4; }

#define WFRAG(P, H) (wlds[(((P) * 2 + (H)) * 4 + q) * 16 + eidx])
#pragma unroll
  for (int h = 0; h < 2; ++h) {
    acc0[h] += mfma16(WFRAG(0, h), b0) * gv0[h];
    const bf16x8 w3 = WFRAG(3, h);
#pragma unroll
    for (int s = 0; s < 3; ++s) acc1[s][h] += mfma16(w3, b1[s]) * gv0[h];
    const bf16x8 w4 = WFRAG(4, h);
#pragma unroll
    for (int s = 0; s < 9; ++s) acc2[s][h] += mfma16(w4, b2[s]) * gv0[h];
  }

  f32x4 gkA[3][2];
#pragma unroll
  for (int j = 0; j < 3; ++j) {
    gkA[j][0] = ntload4(g2p + j * 32);
    gkA[j][1] = ntload4(g2p + j * 32 + 16);
  }

#pragma unroll
  for (int h = 0; h < 2; ++h) {
    {
      const f32x4 t = mfma16(WFRAG(1, h), b0);
#pragma unroll
      for (int s = 0; s < 3; ++s) acc1[s][h] += t * gv1[s][h];
    }
    {
      const bf16x8 w5 = WFRAG(5, h);
#pragma unroll
      for (int s = 0; s < 3; ++s) acc0[h] += mfma16(w5, b1[s]) * gv1[s][h];
    }
    {
      const bf16x8 w6 = WFRAG(6, h);
      const f32x4 c0 = mfma16(w6, b1[0]);
      const f32x4 c1 = mfma16(w6, b1[1]);
      const f32x4 c2 = mfma16(w6, b1[2]);
      acc1[0][h] += c1 * gv1[2][h] - c2 * gv1[1][h];
      acc1[1][h] += c2 * gv1[0][h] - c0 * gv1[2][h];
      acc1[2][h] += c0 * gv1[1][h] - c1 * gv1[0][h];
    }
    {
      const bf16x8 w7 = WFRAG(7, h);
      const f32x4 o0 = mfma16(w7, b1[0]);
      const f32x4 o1 = mfma16(w7, b1[1]);
      const f32x4 o2 = mfma16(w7, b1[2]);
      const f32x4 tr3 = (o0 * gv1[0][h] + o1 * gv1[1][h] + o2 * gv1[2][h]) * (1.f / 3.f);
      acc2[0][h] += o0 * gv1[0][h] - tr3;
      acc2[1][h] += o0 * gv1[1][h];
      acc2[2][h] += o0 * gv1[2][h];
      acc2[3][h] += o1 * gv1[0][h];
      acc2[4][h] += o1 * gv1[1][h] - tr3;
      acc2[5][h] += o1 * gv1[2][h];
      acc2[6][h] += o2 * gv1[0][h];
      acc2[7][h] += o2 * gv1[1][h];
      acc2[8][h] += o2 * gv1[2][h] - tr3;
    }
    {
      const bf16x8 w8 = WFRAG(8, h);
#pragma unroll
      for (int a = 0; a < 3; ++a)
#pragma unroll
        for (int b = 0; b < 3; ++b)
          acc1[a][h] += mfma16(w8, b2[a * 3 + b]) * gv1[b][h];
    }
  }

  f32x4 gkB[3][2];
#pragma unroll
  for (int j = 0; j < 3; ++j) {
    gkB[j][0] = ntload4(g2p + (3 + j) * 32);
    gkB[j][1] = ntload4(g2p + (3 + j) * 32 + 16);
  }

  f32x4 t2[2];
  t2[0] = mfma16(WFRAG(2, 0), b0);
  t2[1] = mfma16(WFRAG(2, 1), b0);

#define G2ROW_COMPUTE(K, GK)                                                   \
  {                                                                            \
    _Pragma("unroll")                                                          \
    for (int h = 0; h < 2; ++h) {                                              \
      _Pragma("unroll")                                                        \
      for (int j = 0; j < 3; ++j) acc2[(K) * 3 + j][h] += t2[h] * GK[j][h];    \
      {                                                                        \
        const f32x4 vk = mfma16(WFRAG(9, h), b1[(K)]);                         \
        _Pragma("unroll")                                                      \
        for (int j = 0; j < 3; ++j) acc1[j][h] += vk * GK[j][h];               \
      }                                                                        \
      {                                                                        \
        const bf16x8 w10 = WFRAG(10, h);                                       \
        _Pragma("unroll")                                                      \
        for (int j = 0; j < 3; ++j)                                            \
          acc0[h] += mfma16(w10, b2[(K) * 3 + j]) * GK[j][h];                  \
      }                                                                        \
      {                                                                        \
        const bf16x8 w11 = WFRAG(11, h);                                       \
        const f32x4 m0 = mfma16(w11, b2[0 * 3 + (K)]);                         \
        const f32x4 m1 = mfma16(w11, b2[1 * 3 + (K)]);                         \
        const f32x4 m2 = mfma16(w11, b2[2 * 3 + (K)]);                         \
        const f32x4 tk3 =                                                      \
            (m0 * GK[0][h] + m1 * GK[1][h] + m2 * GK[2][h]) * (1.f / 3.f);     \
        acc2[0][h] += m0 * GK[0][h] - tk3;                                     \
        acc2[4][h] += m1 * GK[1][h] - tk3;                                     \
        acc2[8][h] += m2 * GK[2][h] - tk3;                                     \
        const f32x4 s01 = (m0 * GK[1][h] + m1 * GK[0][h]) * 0.5f;              \
        acc2[1][h] += s01; acc2[3][h] += s01;                                  \
        const f32x4 s02 = (m0 * GK[2][h] + m2 * GK[0][h]) * 0.5f;              \
        acc2[2][h] += s02; acc2[6][h] += s02;                                  \
        const f32x4 s12 = (m1 * GK[2][h] + m2 * GK[1][h]) * 0.5f;              \
        acc2[5][h] += s12; acc2[7][h] += s12;                                  \
      }                                                                        \
    }                                                                          \
  }

  G2ROW_COMPUTE(0, gkA)
#pragma unroll
  for (int j = 0; j < 3; ++j) {
    gkA[j][0] = ntload4(g2p + (6 + j) * 32);
    gkA[j][1] = ntload4(g2p + (6 + j) * 32 + 16);
  }
  G2ROW_COMPUTE(1, gkB)
  G2ROW_COMPUTE(2, gkA)
#undef G2ROW_COMPUTE

  float* o0p = out + (long long)e * 32 + col;
  float* o1p = out + (long long)E * 32 + (long long)e * 96 + col;
  float* o2p = out + (long long)E * 128 + (long long)e * 288 + col;
  ntstore4(o0p, acc0[0]);
  ntstore4(o0p + 16, acc0[1]);
#pragma unroll
  for (int s = 0; s < 3; ++s) {
    ntstore4(o1p + s * 32, acc1[s][0]);
    ntstore4(o1p + s * 32 + 16, acc1[s][1]);
  }
#pragma unroll
  for (int s = 0; s < 9; ++s) {
    ntstore4(o2p + s * 32, acc2[s][0]);
    ntstore4(o2p + s * 32 + 16, acc2[s][1]);
  }
#undef WFRAG
}

extern "C" void kernel_launch(void* const* d_in, const int* in_sizes, int n_in,
                              void* d_out, int out_size, void* d_ws, size_t ws_size,
                              hipStream_t stream) {
  const float* h0 = (const float*)d_in[0];
  const float* h1 = (const float*)d_in[1];
  const float* h2 = (const float*)d_in[2];
  const float* g0 = (const float*)d_in[3];
  const float* g1 = (const float*)d_in[4];
  const float* g2 = (const float*)d_in[5];
  const float* Wg = (const float*)d_in[6];
  const int* src = (const int*)d_in[7];  // harness passes integer inputs as int32
  const int E = in_sizes[7];
  const int n0 = in_sizes[0], n1 = in_sizes[1], n2 = in_sizes[2];

  const size_t need = 24576 + (size_t)(n0 + n1 + n2) * 2;
  if (ws_size >= need) {
    __bf16* ws = (__bf16*)d_ws;
    leibniz_prepass<<<2048, 256, 0, stream>>>(h0, h1, h2, Wg, ws, n0, n1, n2);
    const int NT = (E + 15) / 16;
    int blocks = 768;                 // 256 CU x 3 blocks (LDS 53KB -> 3/CU)
    if (blocks > NT) blocks = NT;
    leibniz_dma<<<blocks, 128, 0, stream>>>(ws, g0, g1, g2, src,
                                            (float*)d_out, E, n0, n1);
  } else {
    leibniz_fused<<<(E + 63) / 64, 256, 0, stream>>>(h0, h1, h2, g0, g1, g2,
                                                     Wg, src, (float*)d_out, E);
  }
}

// Round 13
// 150.929 us; speedup vs baseline: 1.1346x; 1.1346x over previous
//
#include <hip/hip_runtime.h>

typedef float f32x4 __attribute__((ext_vector_type(4)));
typedef __bf16 bf16x8 __attribute__((ext_vector_type(8)));
typedef __bf16 bf16x4 __attribute__((ext_vector_type(4)));

constexpr float INV_SQRT_F = 0.17677669529663687f;  // 32^-0.5

__device__ __forceinline__ f32x4 mfma16(bf16x8 a, bf16x8 b) {
  const f32x4 z = {0.f, 0.f, 0.f, 0.f};
  return __builtin_amdgcn_mfma_f32_16x16x32_bf16(a, b, z, 0, 0, 0);
}
__device__ __forceinline__ f32x4 ld4(const float* p) {
  return *reinterpret_cast<const f32x4*>(p);
}
__device__ __forceinline__ bf16x8 ldb8(const __bf16* __restrict__ p) {
  return *reinterpret_cast<const bf16x8*>(p);
}
__device__ __forceinline__ bf16x8 cvt_frag(f32x4 u, f32x4 v) {
  bf16x8 r;
  r[0] = (__bf16)u[0]; r[1] = (__bf16)u[1]; r[2] = (__bf16)u[2]; r[3] = (__bf16)u[3];
  r[4] = (__bf16)v[0]; r[5] = (__bf16)v[1]; r[6] = (__bf16)v[2]; r[7] = (__bf16)v[3];
  return r;
}

// ---------------- pre-pass: h -> bf16, W -> scaled frag-layout bf16 --------
// ws layout: [0,24576)B W frags (1536 x bf16x8); then hb0|hb1|hb2 bf16.
__global__ __launch_bounds__(256)
void leibniz_prepass(const float* __restrict__ h0, const float* __restrict__ h1,
                     const float* __restrict__ h2, const float* __restrict__ Wg,
                     __bf16* __restrict__ ws, int n0, int n1, int n2)
{
  if (blockIdx.x == 0) {
    bf16x8* wsW = reinterpret_cast<bf16x8*>(ws);
    for (int c = threadIdx.x; c < 12 * 2 * 4 * 16; c += 256) {
      const int gl = c & 15;
      const int qq = (c >> 4) & 3;
      const int hf = (c >> 6) & 1;
      const int p  = c >> 7;
      const float* wp = Wg + (p * 32 + hf * 16 + gl) * 32 + qq * 8;
      bf16x8 f;
#pragma unroll
      for (int j = 0; j < 8; ++j) f[j] = (__bf16)(wp[j] * INV_SQRT_F);
      wsW[c] = f;
    }
  }
  __bf16* hb0 = ws + 12288;
  __bf16* hb1 = hb0 + n0;
  __bf16* hb2 = hb1 + n1;
  const int q0 = n0 >> 2, q1 = n1 >> 2, q2 = n2 >> 2;
  const int total = q0 + q1 + q2;
  for (int i = blockIdx.x * 256 + threadIdx.x; i < total; i += gridDim.x * 256) {
    const float* sp;
    __bf16* dp;
    if (i < q0)           { sp = h0 + 4 * i;              dp = hb0 + 4 * i; }
    else if (i < q0 + q1) { int j = i - q0;      sp = h1 + 4 * j; dp = hb1 + 4 * j; }
    else                  { int j = i - q0 - q1; sp = h2 + 4 * j; dp = hb2 + 4 * j; }
    const f32x4 v = *reinterpret_cast<const f32x4*>(sp);
    bf16x4 o;
    o[0] = (__bf16)v[0]; o[1] = (__bf16)v[1]; o[2] = (__bf16)v[2]; o[3] = (__bf16)v[3];
    *reinterpret_cast<bf16x4*>(dp) = o;
  }
}

// ---------------- main: persistent half-split waves, W in registers --------
// R11's proven layout/compute (waves 2t/2t+1 = same 16-edge tile, parity =
// feature half; lane owns a contiguous feature float4 per (edge,spatial)
// row; all 26 loads batch-issued -> one wait -> 54 MFMAs -> stores), with
// the per-tile fixed costs removed: persistent blocks grid-stride over
// tile-pairs (launch/teardown amortized ~4x), W held in 12 bf16x8 registers
// per wave (no LDS, no __syncthreads, no per-block W reload). Budget:
// acc 52 + g 52 + h 52 + W 48 + temps ~= 215 regs -> (256,2), no spill.
__global__ __launch_bounds__(256, 2)
void leibniz_persist(const __bf16* __restrict__ wsAll,
                     const float* __restrict__ g0, const float* __restrict__ g1,
                     const float* __restrict__ g2, const int* __restrict__ src,
                     float* __restrict__ out, int E, int n0, int n1)
{
  const int lane  = threadIdx.x & 63;
  const int wid   = threadIdx.x >> 6;
  const int half  = wid & 1;     // feature half owned by this wave
  const int tpair = wid >> 1;    // tile slot within block (0,1)
  const int eidx  = lane & 15;   // edge within tile
  const int q     = lane >> 4;   // feature quad (within half)
  const int col   = q * 4 + 16 * half;

  // W fragments for MY half -> 12 x bf16x8 (48 VGPRs), loaded once
  bf16x8 w[12];
  {
    const bf16x8* wsW = reinterpret_cast<const bf16x8*>(wsAll);
#pragma unroll
    for (int p = 0; p < 12; ++p) w[p] = wsW[(p * 2 + half) * 64 + q * 16 + eidx];
  }
  const __bf16* hb0 = wsAll + 12288;
  const __bf16* hb1 = hb0 + n0;
  const __bf16* hb2 = hb1 + n1;

  const int NT   = (E + 15) >> 4;           // 16-edge tiles
  const int NT2  = (NT + 1) >> 1;           // tile-pairs
  const int nb   = gridDim.x;
  const int iters = (NT2 + nb - 1) / nb;
  const long long o1base = (long long)E * 32;
  const long long o2base = (long long)E * 128;

  for (int it = 0; it < iters; ++it) {
    const int tp = blockIdx.x + it * nb;
    int tile = tp * 2 + tpair;
    const bool active = tile < NT;
    if (active) {
      long long e0 = (long long)tile * 16;
      if (e0 > E - 16) e0 = E - 16;  // benign clamp
      const int node = src[e0 + eidx];
      const long long e = e0 + eidx;

      // ---- batch-issue ALL loads: g first (HBM), then h (ws, L3-resident)
      const float* g0p = g0 + e * 32 + col;
      const float* g1p = g1 + e * 96 + col;
      const float* g2p = g2 + e * 288 + col;
      const f32x4 gv0 = ld4(g0p);
      f32x4 gv1[3];
#pragma unroll
      for (int s = 0; s < 3; ++s) gv1[s] = ld4(g1p + s * 32);
      f32x4 gk[9];
#pragma unroll
      for (int s = 0; s < 9; ++s) gk[s] = ld4(g2p + s * 32);

      const int k0 = q * 8;
      const bf16x8 b0 = ldb8(hb0 + (long long)node * 32 + k0);
      bf16x8 b1[3];
#pragma unroll
      for (int s = 0; s < 3; ++s)
        b1[s] = ldb8(hb1 + (long long)node * 96 + s * 32 + k0);
      bf16x8 b2[9];
#pragma unroll
      for (int s = 0; s < 9; ++s)
        b2[s] = ldb8(hb2 + (long long)node * 288 + s * 32 + k0);

      // ---- g0 phase: paths 0,3,4 (prod); accs initialized here
      f32x4 acc0 = mfma16(w[0], b0) * gv0;
      f32x4 acc1[3];
      f32x4 acc2[9];
#pragma unroll
      for (int s = 0; s < 3; ++s) acc1[s] = mfma16(w[3], b1[s]) * gv0;
#pragma unroll
      for (int s = 0; s < 9; ++s) acc2[s] = mfma16(w[4], b2[s]) * gv0;

      // ---- g1 phase: paths 1 (prod), 5 (dot), 6 (cross), 7 (outer), 8 (mat_vec)
      {
        const f32x4 t = mfma16(w[1], b0);
#pragma unroll
        for (int s = 0; s < 3; ++s) acc1[s] += t * gv1[s];
      }
#pragma unroll
      for (int s = 0; s < 3; ++s) acc0 += mfma16(w[5], b1[s]) * gv1[s];
      {
        const f32x4 c0 = mfma16(w[6], b1[0]);
        const f32x4 c1 = mfma16(w[6], b1[1]);
        const f32x4 c2 = mfma16(w[6], b1[2]);
        acc1[0] += c1 * gv1[2] - c2 * gv1[1];
        acc1[1] += c2 * gv1[0] - c0 * gv1[2];
        acc1[2] += c0 * gv1[1] - c1 * gv1[0];
      }
      {
        const f32x4 o0 = mfma16(w[7], b1[0]);
        const f32x4 o1 = mfma16(w[7], b1[1]);
        const f32x4 o2 = mfma16(w[7], b1[2]);
        const f32x4 tr3 = (o0 * gv1[0] + o1 * gv1[1] + o2 * gv1[2]) * (1.f / 3.f);
        acc2[0] += o0 * gv1[0] - tr3;
        acc2[1] += o0 * gv1[1];
        acc2[2] += o0 * gv1[2];
        acc2[3] += o1 * gv1[0];
        acc2[4] += o1 * gv1[1] - tr3;
        acc2[5] += o1 * gv1[2];
        acc2[6] += o2 * gv1[0];
        acc2[7] += o2 * gv1[1];
        acc2[8] += o2 * gv1[2] - tr3;
      }
#pragma unroll
      for (int a = 0; a < 3; ++a)
#pragma unroll
        for (int b = 0; b < 3; ++b)
          acc1[a] += mfma16(w[8], b2[a * 3 + b]) * gv1[b];

      // ---- g2 phase: paths 2 (prod), 9 (vec_mat), 10 (double_dot), 11 (sym)
      {
        const f32x4 t2 = mfma16(w[2], b0);
#pragma unroll
        for (int ss = 0; ss < 9; ++ss) acc2[ss] += t2 * gk[ss];
      }
#pragma unroll
      for (int i = 0; i < 3; ++i) {
        const f32x4 vk = mfma16(w[9], b1[i]);
#pragma unroll
        for (int j = 0; j < 3; ++j) acc1[j] += vk * gk[i * 3 + j];
      }
#pragma unroll
      for (int ss = 0; ss < 9; ++ss) acc0 += mfma16(w[10], b2[ss]) * gk[ss];
#pragma unroll
      for (int k = 0; k < 3; ++k) {
        const f32x4 m0 = mfma16(w[11], b2[0 * 3 + k]);
        const f32x4 m1 = mfma16(w[11], b2[1 * 3 + k]);
        const f32x4 m2 = mfma16(w[11], b2[2 * 3 + k]);
        const f32x4 gk0 = gk[k * 3 + 0];
        const f32x4 gk1 = gk[k * 3 + 1];
        const f32x4 gk2 = gk[k * 3 + 2];
        const f32x4 tk3 = (m0 * gk0 + m1 * gk1 + m2 * gk2) * (1.f / 3.f);
        acc2[0] += m0 * gk0 - tk3;
        acc2[4] += m1 * gk1 - tk3;
        acc2[8] += m2 * gk2 - tk3;
        const f32x4 s01 = (m0 * gk1 + m1 * gk0) * 0.5f;
        acc2[1] += s01; acc2[3] += s01;
        const f32x4 s02 = (m0 * gk2 + m2 * gk0) * 0.5f;
        acc2[2] += s02; acc2[6] += s02;
        const f32x4 s12 = (m1 * gk2 + m2 * gk1) * 0.5f;
        acc2[5] += s12; acc2[7] += s12;
      }

      __builtin_amdgcn_s_barrier();  // align pair store bursts (sector merge)

      // ---- stores: 16B/row; pair covers both 64B sectors of each line
      float* o0p = out + e * 32 + col;
      float* o1p = out + o1base + e * 96 + col;
      float* o2p = out + o2base + e * 288 + col;
      *reinterpret_cast<f32x4*>(o0p) = acc0;
#pragma unroll
      for (int s = 0; s < 3; ++s)
        *reinterpret_cast<f32x4*>(o1p + s * 32) = acc1[s];
#pragma unroll
      for (int s = 0; s < 9; ++s)
        *reinterpret_cast<f32x4*>(o2p + s * 32) = acc2[s];
    } else {
      __builtin_amdgcn_s_barrier();  // keep block barrier-uniform
    }
  }
}

// ---------------- fallback: R5 fused kernel (127 us, no ws needed) ---------
__device__ __forceinline__ bf16x8 load_frag8(const float* __restrict__ p) {
  return cvt_frag(ld4(p), ld4(p + 4));
}
__device__ __forceinline__ f32x4 ntload4(const float* __restrict__ p) {
  return __builtin_nontemporal_load(reinterpret_cast<const f32x4*>(p));
}
__device__ __forceinline__ void ntstore4(float* __restrict__ p, f32x4 v) {
  __builtin_nontemporal_store(v, reinterpret_cast<f32x4*>(p));
}

__global__ __launch_bounds__(256, 2)
void leibniz_fused(const float* __restrict__ h0, const float* __restrict__ h1,
                   const float* __restrict__ h2, const float* __restrict__ g0,
                   const float* __restrict__ g1, const float* __restrict__ g2,
                   const float* __restrict__ Wg, const int* __restrict__ src,
                   float* __restrict__ out, int E)
{
  __shared__ bf16x8 wlds[12 * 2 * 4 * 16];
  for (int c = threadIdx.x; c < 12 * 2 * 4 * 16; c += 256) {
    const int gl = c & 15;
    const int qq = (c >> 4) & 3;
    const int hf = (c >> 6) & 1;
    const int p  = c >> 7;
    const float* wp = Wg + (p * 32 + hf * 16 + gl) * 32 + qq * 8;
    bf16x8 f;
#pragma unroll
    for (int j = 0; j < 8; ++j) f[j] = (__bf16)(wp[j] * INV_SQRT_F);
    wlds[c] = f;
  }
  __syncthreads();

  const int lane = threadIdx.x & 63;
  const int wid  = threadIdx.x >> 6;
  const int eidx = lane & 15;
  const int q    = lane >> 4;
  int e0 = (blockIdx.x * 4 + wid) * 16;
  if (e0 > E - 16) e0 = E - 16;

  const int node = src[e0 + eidx];
  const int e   = e0 + eidx;
  const int col = q * 4;
  const float* g0p = g0 + e * 32 + col;
  const float* g1p = g1 + (long long)e * 96 + col;
  const float* g2p = g2 + (long long)e * 288 + col;

  f32x4 gv0[2];
  gv0[0] = ntload4(g0p); gv0[1] = ntload4(g0p + 16);
  f32x4 gv1[3][2];
#pragma unroll
  for (int s = 0; s < 3; ++s) {
    gv1[s][0] = ntload4(g1p + s * 32);
    gv1[s][1] = ntload4(g1p + s * 32 + 16);
  }

  const int k0 = q * 8;
  const bf16x8 b0 = load_frag8(h0 + node * 32 + k0);
  bf16x8 b1[3];
#pragma unroll
  for (int s = 0; s < 3; ++s) b1[s] = load_frag8(h1 + node * 96 + s * 32 + k0);
  bf16x8 b2[9];
#pragma unroll
  for (int s = 0; s < 9; ++s) b2[s] = load_frag8(h2 + node * 288 + s * 32 + k0);

  const f32x4 z4 = {0.f, 0.f, 0.f, 0.f};
  f32x4 acc0[2] = {z4, z4};
  f32x4 acc1[3][2];
  f32x4 acc2[9][2];
#pragma unroll
  for (int s = 0; s < 3; ++s) { acc1[s][0] = z4; acc1[s][1] = z4; }
#pragma unroll
  for (int s = 0; s < 9; ++s) { acc2[s][0] = z4; acc2[s][1] = z4; }

#define WFRAG(P, H) (wlds[(((P) * 2 + (H)) * 4 + q) * 16 + eidx])
#pragma unroll
  for (int h = 0; h < 2; ++h) {
    acc0[h] += mfma16(WFRAG(0, h), b0) * gv0[h];
    const bf16x8 w3 = WFRAG(3, h);
#pragma unroll
    for (int s = 0; s < 3; ++s) acc1[s][h] += mfma16(w3, b1[s]) * gv0[h];
    const bf16x8 w4 = WFRAG(4, h);
#pragma unroll
    for (int s = 0; s < 9; ++s) acc2[s][h] += mfma16(w4, b2[s]) * gv0[h];
  }

  f32x4 gkA[3][2];
#pragma unroll
  for (int j = 0; j < 3; ++j) {
    gkA[j][0] = ntload4(g2p + j * 32);
    gkA[j][1] = ntload4(g2p + j * 32 + 16);
  }

#pragma unroll
  for (int h = 0; h < 2; ++h) {
    {
      const f32x4 t = mfma16(WFRAG(1, h), b0);
#pragma unroll
      for (int s = 0; s < 3; ++s) acc1[s][h] += t * gv1[s][h];
    }
    {
      const bf16x8 w5 = WFRAG(5, h);
#pragma unroll
      for (int s = 0; s < 3; ++s) acc0[h] += mfma16(w5, b1[s]) * gv1[s][h];
    }
    {
      const bf16x8 w6 = WFRAG(6, h);
      const f32x4 c0 = mfma16(w6, b1[0]);
      const f32x4 c1 = mfma16(w6, b1[1]);
      const f32x4 c2 = mfma16(w6, b1[2]);
      acc1[0][h] += c1 * gv1[2][h] - c2 * gv1[1][h];
      acc1[1][h] += c2 * gv1[0][h] - c0 * gv1[2][h];
      acc1[2][h] += c0 * gv1[1][h] - c1 * gv1[0][h];
    }
    {
      const bf16x8 w7 = WFRAG(7, h);
      const f32x4 o0 = mfma16(w7, b1[0]);
      const f32x4 o1 = mfma16(w7, b1[1]);
      const f32x4 o2 = mfma16(w7, b1[2]);
      const f32x4 tr3 = (o0 * gv1[0][h] + o1 * gv1[1][h] + o2 * gv1[2][h]) * (1.f / 3.f);
      acc2[0][h] += o0 * gv1[0][h] - tr3;
      acc2[1][h] += o0 * gv1[1][h];
      acc2[2][h] += o0 * gv1[2][h];
      acc2[3][h] += o1 * gv1[0][h];
      acc2[4][h] += o1 * gv1[1][h] - tr3;
      acc2[5][h] += o1 * gv1[2][h];
      acc2[6][h] += o2 * gv1[0][h];
      acc2[7][h] += o2 * gv1[1][h];
      acc2[8][h] += o2 * gv1[2][h] - tr3;
    }
    {
      const bf16x8 w8 = WFRAG(8, h);
#pragma unroll
      for (int a = 0; a < 3; ++a)
#pragma unroll
        for (int b = 0; b < 3; ++b)
          acc1[a][h] += mfma16(w8, b2[a * 3 + b]) * gv1[b][h];
    }
  }

  f32x4 gkB[3][2];
#pragma unroll
  for (int j = 0; j < 3; ++j) {
    gkB[j][0] = ntload4(g2p + (3 + j) * 32);
    gkB[j][1] = ntload4(g2p + (3 + j) * 32 + 16);
  }

  f32x4 t2[2];
  t2[0] = mfma16(WFRAG(2, 0), b0);
  t2[1] = mfma16(WFRAG(2, 1), b0);

#define G2ROW_COMPUTE(K, GK)                                                   \
  {                                                                            \
    _Pragma("unroll")                                                          \
    for (int h = 0; h < 2; ++h) {                                              \
      _Pragma("unroll")                                                        \
      for (int j = 0; j < 3; ++j) acc2[(K) * 3 + j][h] += t2[h] * GK[j][h];    \
      {                                                                        \
        const f32x4 vk = mfma16(WFRAG(9, h), b1[(K)]);                         \
        _Pragma("unroll")                                                      \
        for (int j = 0; j < 3; ++j) acc1[j][h] += vk * GK[j][h];               \
      }                                                                        \
      {                                                                        \
        const bf16x8 w10 = WFRAG(10, h);                                       \
        _Pragma("unroll")                                                      \
        for (int j = 0; j < 3; ++j)                                            \
          acc0[h] += mfma16(w10, b2[(K) * 3 + j]) * GK[j][h];                  \
      }                                                                        \
      {                                                                        \
        const bf16x8 w11 = WFRAG(11, h);                                       \
        const f32x4 m0 = mfma16(w11, b2[0 * 3 + (K)]);                         \
        const f32x4 m1 = mfma16(w11, b2[1 * 3 + (K)]);                         \
        const f32x4 m2 = mfma16(w11, b2[2 * 3 + (K)]);                         \
        const f32x4 tk3 =                                                      \
            (m0 * GK[0][h] + m1 * GK[1][h] + m2 * GK[2][h]) * (1.f / 3.f);     \
        acc2[0][h] += m0 * GK[0][h] - tk3;                                     \
        acc2[4][h] += m1 * GK[1][h] - tk3;                                     \
        acc2[8][h] += m2 * GK[2][h] - tk3;                                     \
        const f32x4 s01 = (m0 * GK[1][h] + m1 * GK[0][h]) * 0.5f;              \
        acc2[1][h] += s01; acc2[3][h] += s01;                                  \
        const f32x4 s02 = (m0 * GK[2][h] + m2 * GK[0][h]) * 0.5f;              \
        acc2[2][h] += s02; acc2[6][h] += s02;                                  \
        const f32x4 s12 = (m1 * GK[2][h] + m2 * GK[1][h]) * 0.5f;              \
        acc2[5][h] += s12; acc2[7][h] += s12;                                  \
      }                                                                        \
    }                                                                          \
  }

  G2ROW_COMPUTE(0, gkA)
#pragma unroll
  for (int j = 0; j < 3; ++j) {
    gkA[j][0] = ntload4(g2p + (6 + j) * 32);
    gkA[j][1] = ntload4(g2p + (6 + j) * 32 + 16);
  }
  G2ROW_COMPUTE(1, gkB)
  G2ROW_COMPUTE(2, gkA)
#undef G2ROW_COMPUTE

  float* o0p = out + (long long)e * 32 + col;
  float* o1p = out + (long long)E * 32 + (long long)e * 96 + col;
  float* o2p = out + (long long)E * 128 + (long long)e * 288 + col;
  ntstore4(o0p, acc0[0]);
  ntstore4(o0p + 16, acc0[1]);
#pragma unroll
  for (int s = 0; s < 3; ++s) {
    ntstore4(o1p + s * 32, acc1[s][0]);
    ntstore4(o1p + s * 32 + 16, acc1[s][1]);
  }
#pragma unroll
  for (int s = 0; s < 9; ++s) {
    ntstore4(o2p + s * 32, acc2[s][0]);
    ntstore4(o2p + s * 32 + 16, acc2[s][1]);
  }
#undef WFRAG
}

extern "C" void kernel_launch(void* const* d_in, const int* in_sizes, int n_in,
                              void* d_out, int out_size, void* d_ws, size_t ws_size,
                              hipStream_t stream) {
  const float* h0 = (const float*)d_in[0];
  const float* h1 = (const float*)d_in[1];
  const float* h2 = (const float*)d_in[2];
  const float* g0 = (const float*)d_in[3];
  const float* g1 = (const float*)d_in[4];
  const float* g2 = (const float*)d_in[5];
  const float* Wg = (const float*)d_in[6];
  const int* src = (const int*)d_in[7];  // harness passes integer inputs as int32
  const int E = in_sizes[7];
  const int n0 = in_sizes[0], n1 = in_sizes[1], n2 = in_sizes[2];

  const size_t need = 24576 + (size_t)(n0 + n1 + n2) * 2;
  if (ws_size >= need) {
    __bf16* ws = (__bf16*)d_ws;
    leibniz_prepass<<<2048, 256, 0, stream>>>(h0, h1, h2, Wg, ws, n0, n1, n2);
    const int NT  = (E + 15) / 16;
    const int NT2 = (NT + 1) / 2;
    int blocks = 1024;                 // persistent: ~4 tile-pairs per block
    if (blocks > NT2) blocks = NT2;
    leibniz_persist<<<blocks, 256, 0, stream>>>(ws, g0, g1, g2, src,
                                                (float*)d_out, E, n0, n1);
  } else {
    leibniz_fused<<<(E + 63) / 64, 256, 0, stream>>>(h0, h1, h2, g0, g1, g2,
                                                     Wg, src, (float*)d_out, E);
  }
}